// Round 8
// baseline (271.821 us; speedup 1.0000x reference)
//
#include <hip/hip_runtime.h>
#include <hip/hip_bf16.h>
#include <hip/hip_fp16.h>

#define D_MODEL 1024
#define N_HEADS 16
#define HEAD_DIM 64
#define NUM_RULES 64
#define RANK 8
#define SHARED_RANK 32
#define NUM_BLOCKS_ 16
#define BB 4
#define SS 1024
#define NTOK (BB*SS)
#define NGRP (NTOK/8)   // 512 token-groups of 8 (stage A)
#define NGRP4 (NTOK/4)  // 1024 blocks of 4 tokens (stage B)

typedef __attribute__((ext_vector_type(8))) short bf16x8;   // 8 bf16 = 4 VGPR
typedef __attribute__((ext_vector_type(4))) float f32x4;

__device__ __forceinline__ float bf2f(unsigned short u) {
  unsigned int i = ((unsigned int)u) << 16;
  float f;
  __builtin_memcpy(&f, &i, 4);
  return f;
}
__device__ __forceinline__ unsigned short f2bf(float f) {
  __hip_bfloat16 h = __float2bfloat16(f);
  unsigned short u;
  __builtin_memcpy(&u, &h, 2);
  return u;
}
__device__ __forceinline__ unsigned short f2h(float f) {
  __half h = __float2half(f);
  unsigned short u;
  __builtin_memcpy(&u, &h, 2);
  return u;
}
__device__ __forceinline__ float h2f(unsigned short u) {
  __half h;
  __builtin_memcpy(&h, &u, 2);
  return __half2float(h);
}
template<bool BF>
__device__ __forceinline__ float ldw(const void* p, size_t i) {
  if (BF) return bf2f(((const unsigned short*)p)[i]);
  else    return ((const float*)p)[i];
}

// ---------------------------------------------------------------------------
// Dtype detection
// ---------------------------------------------------------------------------
__global__ void detect_kernel(const unsigned short* __restrict__ x, int* __restrict__ flag) {
  const int lane = threadIdx.x;  // 64
  int good = 0;
  for (int i = 0; i < 4; i++) {
    unsigned short u = x[lane*4 + i];
    int e = (u >> 7) & 0xFF;
    good += (e == 0 || (e >= 100 && e <= 145)) ? 1 : 0;
  }
  for (int off = 32; off; off >>= 1) good += __shfl_xor(good, off);
  if (lane == 0) flag[0] = (good >= 224) ? 1 : 0;
}

// ---------------------------------------------------------------------------
// Precompute: M[64][64] and sel[4][64][16]
// ---------------------------------------------------------------------------
template<bool BF>
__device__ __forceinline__ void precompute_body(
    const void* rq, const void* rk,
    const void* qlg, const void* klg, const void* vlg, const void* olg,
    float* __restrict__ M, float* __restrict__ sel)
{
  __shared__ float rqn[64][8], rkn[64][8];
  const int tid = threadIdx.x;  // 256
  if (tid < 64) {
    float v[8]; float s = 0.f;
    for (int i = 0; i < 8; i++) { v[i] = ldw<BF>(rq, tid*8+i); s += v[i]*v[i]; }
    float inv = 1.0f / fmaxf(sqrtf(s), 1e-12f);
    for (int i = 0; i < 8; i++) rqn[tid][i] = v[i]*inv;
  } else if (tid < 128) {
    int r = tid - 64;
    float v[8]; float s = 0.f;
    for (int i = 0; i < 8; i++) { v[i] = ldw<BF>(rk, r*8+i); s += v[i]*v[i]; }
    float inv = 1.0f / fmaxf(sqrtf(s), 1e-12f);
    for (int i = 0; i < 8; i++) rkn[r][i] = v[i]*inv;
  }
  __syncthreads();
  const float LN8 = 2.0794415416798357f;  // 1/tau = ln(8)
  for (int idx = tid; idx < 64*64; idx += 256) {
    int i = idx >> 6, j = idx & 63;
    float d = 0.f;
    for (int t = 0; t < 8; t++) d += rqn[i][t]*rkn[j][t];
    M[idx] = d * LN8;
  }
  const void* lgs[4] = {qlg, klg, vlg, olg};
  {
    int r = tid & 63;
    const void* lg = lgs[tid >> 6];
    float e[NUM_BLOCKS_]; float mx = -1e30f;
    for (int b = 0; b < NUM_BLOCKS_; b++) {
      e[b] = ldw<BF>(lg, r*NUM_BLOCKS_ + b) * 4.0f;
      mx = fmaxf(mx, e[b]);
    }
    float s = 0.f;
    for (int b = 0; b < NUM_BLOCKS_; b++) { e[b] = expf(e[b]-mx); s += e[b]; }
    float inv = 1.0f/s;
    for (int b = 0; b < NUM_BLOCKS_; b++) sel[tid*NUM_BLOCKS_+b] = e[b]*inv;
  }
}

__global__ void precompute_kernel(
    const void* rq, const void* rk,
    const void* qlg, const void* klg, const void* vlg, const void* olg,
    float* M, float* sel, const int* __restrict__ flag)
{
  if (*flag) precompute_body<true >(rq, rk, qlg, klg, vlg, olg, M, sel);
  else       precompute_body<false>(rq, rk, qlg, klg, vlg, olg, M, sel);
}

// ---------------------------------------------------------------------------
// prep_wb: pack si (q,k,v,o) into MFMA-B-fragment order, split bf16 hi/lo.
// ---------------------------------------------------------------------------
__global__ __launch_bounds__(128) void prep_wb_kernel(
    const float* __restrict__ qsi, const float* __restrict__ ksi,
    const float* __restrict__ vsi, const float* __restrict__ osi,
    unsigned short* __restrict__ wh, unsigned short* __restrict__ wl,
    const int* __restrict__ flag)
{
  if (*flag) return;
  const int kt = blockIdx.x, p = blockIdx.y;
  const int tid = threadIdx.x, nt = tid >> 6, lane = tid & 63;
  const float* si = (p==0)?qsi:((p==1)?ksi:((p==2)?vsi:osi));
  const int col = nt*16 + (lane & 15);
  const int k0 = kt*32 + (lane >> 4)*8;
  size_t base = ((((size_t)p*32 + kt)*2 + nt)*64 + lane)*8;
  unsigned short h8[8], l8[8];
  #pragma unroll
  for (int j = 0; j < 8; j++) {
    float f = si[(size_t)(k0 + j)*SHARED_RANK + col];
    unsigned short hu = f2bf(f);
    h8[j] = hu;
    l8[j] = f2bf(f - bf2f(hu));
  }
  #pragma unroll
  for (int j = 0; j < 8; j++) { wh[base + j] = h8[j]; wl[base + j] = l8[j]; }
}

// ---------------------------------------------------------------------------
// A_tt_mfma: tt[y][n][32] = x @ si  via split-bf16 MFMA (3 passes).
// ---------------------------------------------------------------------------
template<int NPROJ>
__device__ __forceinline__ void tt_mfma_body(
    const float* __restrict__ xin,
    const unsigned short* __restrict__ wh, const unsigned short* __restrict__ wl,
    int p0, float* __restrict__ ttg)
{
  const int NT = NPROJ*2;
  const int tile = blockIdx.x;          // 16-token tile
  const int tid = threadIdx.x, lane = tid & 63, w = tid >> 6;
  const int kq = lane >> 4;
  __shared__ float red[4][64][25];      // pad 25: conflict-free reduce

  f32x4 acc[NT];
  #pragma unroll
  for (int i = 0; i < NT; i++) acc[i] = (f32x4){0.f,0.f,0.f,0.f};

  const float* xrow = xin + (size_t)(tile*16 + (lane & 15))*D_MODEL + kq*8;
  #pragma unroll 2
  for (int s = 0; s < 8; s++) {
    const int kt = w*8 + s;
    float4 a0 = *(const float4*)(xrow + kt*32);
    float4 a1 = *(const float4*)(xrow + kt*32 + 4);
    float av[8] = {a0.x,a0.y,a0.z,a0.w,a1.x,a1.y,a1.z,a1.w};
    bf16x8 ah, al;
    #pragma unroll
    for (int j = 0; j < 8; j++) {
      unsigned short hu = f2bf(av[j]);
      ah[j] = (short)hu;
      al[j] = (short)f2bf(av[j] - bf2f(hu));
    }
    #pragma unroll
    for (int p = 0; p < NPROJ; p++) {
      #pragma unroll
      for (int nt = 0; nt < 2; nt++) {
        size_t bidx = ((((size_t)(p0+p)*32 + kt)*2 + nt)*64 + lane)*8;
        bf16x8 bh = *(const bf16x8*)(wh + bidx);
        bf16x8 bl = *(const bf16x8*)(wl + bidx);
        f32x4 c = acc[p*2+nt];
        c = __builtin_amdgcn_mfma_f32_16x16x32_bf16(ah, bh, c, 0, 0, 0);
        c = __builtin_amdgcn_mfma_f32_16x16x32_bf16(al, bh, c, 0, 0, 0);
        c = __builtin_amdgcn_mfma_f32_16x16x32_bf16(ah, bl, c, 0, 0, 0);
        acc[p*2+nt] = c;
      }
    }
  }
  #pragma unroll
  for (int i = 0; i < NT; i++) {
    red[w][lane][i*4+0] = acc[i][0]; red[w][lane][i*4+1] = acc[i][1];
    red[w][lane][i*4+2] = acc[i][2]; red[w][lane][i*4+3] = acc[i][3];
  }
  __syncthreads();
  if (w == 0) {
    const int tok0 = tile*16 + (lane >> 4)*4;   // C/D: row=(lane>>4)*4+r
    #pragma unroll
    for (int i = 0; i < NT; i++) {
      const int ys = i >> 1, jj = (i & 1)*16 + (lane & 15);
      #pragma unroll
      for (int r = 0; r < 4; r++) {
        float sum = red[0][lane][i*4+r] + red[1][lane][i*4+r]
                  + red[2][lane][i*4+r] + red[3][lane][i*4+r];
        ttg[((size_t)ys*NTOK + tok0 + r)*32 + jj] = sum;
      }
    }
  }
}

__global__ __launch_bounds__(256) void A_tt_mfma3(
    const float* __restrict__ xin,
    const unsigned short* __restrict__ wh, const unsigned short* __restrict__ wl,
    float* __restrict__ ttg, const int* __restrict__ flag)
{
  if (*flag) return;
  tt_mfma_body<3>(xin, wh, wl, 0, ttg);
}

__global__ __launch_bounds__(256) void A_tt_mfma1(
    const float* __restrict__ xin,
    const unsigned short* __restrict__ wh, const unsigned short* __restrict__ wl,
    float* __restrict__ ttg, const int* __restrict__ flag)
{
  if (*flag) return;
  tt_mfma_body<1>(xin, wh, wl, 3, ttg);
}

// ---------------------------------------------------------------------------
// A_hh: low-rank inner hh[y][n][16][8], LDS-free, q/k/v fused.
// ---------------------------------------------------------------------------
template<int NP>
__device__ __forceinline__ void hh_body(
    const float* __restrict__ xin, const int* __restrict__ rules,
    const float* __restrict__ ri0, const float* __restrict__ ri1,
    const float* __restrict__ ri2, float* __restrict__ hhg)
{
  const int g = blockIdx.x, n0 = g*8, tid = threadIdx.x;
  const int t = tid >> 5, blk = (tid >> 1) & 15, r0 = (tid & 1)*4;
  const int n = n0 + t;
  const int rule = rules[n];
  const float* xb = xin + (size_t)n*D_MODEL + blk*64;
  const float* wb[3];
  wb[0] = ri0 + (size_t)rule*512 + r0;
  if (NP > 1) {
    wb[1] = ri1 + (size_t)rule*512 + r0;
    wb[2] = ri2 + (size_t)rule*512 + r0;
  }
  float a[NP][4];
  #pragma unroll
  for (int p = 0; p < NP; p++) { a[p][0]=0.f; a[p][1]=0.f; a[p][2]=0.f; a[p][3]=0.f; }
  #pragma unroll 4
  for (int k4 = 0; k4 < 16; k4++) {
    float4 xv = *(const float4*)(xb + k4*4);
    #pragma unroll
    for (int q = 0; q < 4; q++) {
      const int k = k4*4 + q;
      float xq = (q==0)?xv.x:((q==1)?xv.y:((q==2)?xv.z:xv.w));
      #pragma unroll
      for (int p = 0; p < NP; p++) {
        float4 wv = *(const float4*)(wb[p] + (size_t)k*8);
        a[p][0] += xq*wv.x; a[p][1] += xq*wv.y; a[p][2] += xq*wv.z; a[p][3] += xq*wv.w;
      }
    }
  }
  #pragma unroll
  for (int p = 0; p < NP; p++) {
    float4 hv; hv.x=a[p][0]; hv.y=a[p][1]; hv.z=a[p][2]; hv.w=a[p][3];
    *(float4*)&hhg[((size_t)p*NTOK + n)*128 + blk*8 + r0] = hv;
  }
}

__global__ __launch_bounds__(256) void A_hh3_f32(
    const float* __restrict__ xin, const int* __restrict__ rules,
    const float* __restrict__ qri, const float* __restrict__ kri,
    const float* __restrict__ vri, float* __restrict__ hhg,
    const int* __restrict__ flag)
{
  if (*flag) return;
  hh_body<3>(xin, rules, qri, kri, vri, hhg);
}

__global__ __launch_bounds__(256) void A_hh1_f32(
    const float* __restrict__ xin, const int* __restrict__ rules,
    const float* __restrict__ ori, float* __restrict__ hhg,
    const int* __restrict__ flag)
{
  if (*flag) return;
  hh_body<1>(xin, rules, ori, ori, ori, hhg);
}

// ---------------------------------------------------------------------------
// Stage A (bf16-input path only): tt + hh fused, LDS-staged.
// ---------------------------------------------------------------------------
template<bool IN_BF, bool W_BF>
__device__ __forceinline__ void stageA_body(
    const void* __restrict__ xin, const int* __restrict__ rules,
    const void* __restrict__ si, const void* __restrict__ ri,
    float* __restrict__ ttg, float* __restrict__ hhg, int yslot)
{
  const int g = blockIdx.x, n0 = g*8, tid = threadIdx.x;
  __shared__ float xs[8][D_MODEL];     // 32 KB
  __shared__ float tpart[8][32][9];    // pad 9: conflict-free reduce
  __shared__ int rl[8];

  #pragma unroll
  for (int t = 0; t < 8; t++) {
    float4 f;
    if (IN_BF) {
      ushort4 u = ((const ushort4*)((const unsigned short*)xin + (size_t)(n0+t)*D_MODEL))[tid];
      f.x = bf2f(u.x); f.y = bf2f(u.y); f.z = bf2f(u.z); f.w = bf2f(u.w);
    } else {
      f = ((const float4*)xin)[(size_t)(n0+t)*(D_MODEL/4) + tid];
    }
    *(float4*)&xs[t][tid*4] = f;
  }
  if (tid < 8) rl[tid] = rules[n0 + tid];
  __syncthreads();

  {
    const int c = tid >> 5, j = tid & 31;
    float p[8];
    #pragma unroll
    for (int t = 0; t < 8; t++) p[t] = 0.f;
    #pragma unroll 4
    for (int d4 = 0; d4 < 32; d4++) {
      const int d = c*128 + d4*4;
      float w0 = ldw<W_BF>(si, (size_t)(d+0)*SHARED_RANK + j);
      float w1 = ldw<W_BF>(si, (size_t)(d+1)*SHARED_RANK + j);
      float w2 = ldw<W_BF>(si, (size_t)(d+2)*SHARED_RANK + j);
      float w3 = ldw<W_BF>(si, (size_t)(d+3)*SHARED_RANK + j);
      #pragma unroll
      for (int t = 0; t < 8; t++) {
        float4 xv = *(const float4*)&xs[t][d];   // broadcast across j-lanes
        p[t] += xv.x*w0 + xv.y*w1 + xv.z*w2 + xv.w*w3;
      }
    }
    #pragma unroll
    for (int t = 0; t < 8; t++) tpart[c][j][t] = p[t];
  }
  __syncthreads();

  {
    const int t = tid >> 5, j = tid & 31;
    float s = 0.f;
    #pragma unroll
    for (int c = 0; c < 8; c++) s += tpart[c][j][t];
    ttg[((size_t)yslot*NTOK + n0 + t)*32 + j] = s;
  }
  {
    const int t = tid >> 5, blk = (tid >> 1) & 15, r0 = (tid & 1)*4;
    const int rule = rl[t];
    float a0=0.f, a1=0.f, a2=0.f, a3=0.f;
    #pragma unroll 4
    for (int k4 = 0; k4 < 16; k4++) {
      const int kk = ((k4 + blk) & 15) * 4;   // rotate: spreads LDS banks
      float4 xv = *(const float4*)&xs[t][blk*64 + kk];
      #pragma unroll
      for (int q = 0; q < 4; q++) {
        const int k = kk + q;
        float w0,w1,w2,w3;
        if (W_BF) {
          ushort4 u = *(const ushort4*)((const unsigned short*)ri + (size_t)rule*512 + (size_t)k*8 + r0);
          w0=bf2f(u.x); w1=bf2f(u.y); w2=bf2f(u.z); w3=bf2f(u.w);
        } else {
          float4 u = *(const float4*)((const float*)ri + (size_t)rule*512 + (size_t)k*8 + r0);
          w0=u.x; w1=u.y; w2=u.z; w3=u.w;
        }
        float xq = (q==0)?xv.x:((q==1)?xv.y:((q==2)?xv.z:xv.w));
        a0 += xq*w0; a1 += xq*w1; a2 += xq*w2; a3 += xq*w3;
      }
    }
    float4 hv; hv.x=a0; hv.y=a1; hv.z=a2; hv.w=a3;
    *(float4*)&hhg[((size_t)yslot*NTOK + n0 + t)*128 + blk*8 + r0] = hv;
  }
}

__global__ __launch_bounds__(256) void A_qkv_bf16(
    const void* x, const int* rules,
    const void* qsi, const void* qri, const void* ksi, const void* kri,
    const void* vsi, const void* vri,
    float* ttg, float* hhg, const int* __restrict__ flag)
{
  if (!*flag) return;
  const int y = blockIdx.y;
  const void* si = (y==0)?qsi:((y==1)?ksi:vsi);
  const void* ri = (y==0)?qri:((y==1)?kri:vri);
  stageA_body<true,true>(x, rules, si, ri, ttg, hhg, y);
}

// o-projection stage A with bf16 weights but fp32 input (attn output)
__global__ __launch_bounds__(256) void A_o_bf16(
    const void* ain, const int* rules, const void* osi, const void* ori,
    float* ttg, float* hhg, const int* __restrict__ flag)
{
  if (!*flag) return;
  stageA_body<false,true>(ain, rules, osi, ori, ttg, hhg, 0);
}

// ---------------------------------------------------------------------------
// Stage B: 4 tokens/block.
// ---------------------------------------------------------------------------
template<bool W_BF>
__device__ __forceinline__ void stageB_body(
    const float* __restrict__ ttg, const float* __restrict__ hhg,
    const int* __restrict__ rules,
    const void* __restrict__ so, const void* __restrict__ ro,
    const float* __restrict__ sel, void* __restrict__ out,
    int yslot, int do_rope, int out_bf)
{
  const int blk4 = blockIdx.x;            // 4-token block
  const int n0 = blk4*4, tid = threadIdx.x;
  __shared__ float tt_lds[32][5];    // [j][t4], pad 5
  __shared__ float hh_lds[4][132];   // [t4][blk*8+r]
  __shared__ int rl[4];

  if (tid < 128) {                    // tt: 32 j x 4 tokens
    const int j = tid >> 2, t4 = tid & 3;
    tt_lds[j][t4] = ttg[((size_t)yslot*NTOK + n0 + t4)*32 + j];
  } else if (tid < 256 && (tid - 128) < 128) {  // hh: 4 tokens x 128 floats
    const int i = tid - 128;
    const int t4 = i >> 5, c = (i*4) & 127;
    float4 hv = *(const float4*)&hhg[((size_t)yslot*NTOK + n0 + t4)*128 + c];
    *(float4*)&hh_lds[t4][c] = hv;
  }
  if (tid < 4) rl[tid] = rules[n0 + tid];
  __syncthreads();

  const int ch0 = tid*4;
  float a0[4], a1[4], a2[4], a3[4];
  #pragma unroll
  for (int t = 0; t < 4; t++) { a0[t]=0.f; a1[t]=0.f; a2[t]=0.f; a3[t]=0.f; }

  #pragma unroll 4
  for (int j = 0; j < 32; j++) {
    float w0, w1, w2, w3;
    if (W_BF) {
      ushort4 u = *(const ushort4*)((const unsigned short*)so + (size_t)j*D_MODEL + ch0);
      w0=bf2f(u.x); w1=bf2f(u.y); w2=bf2f(u.z); w3=bf2f(u.w);
    } else {
      float4 u = *(const float4*)((const float*)so + (size_t)j*D_MODEL + ch0);
      w0=u.x; w1=u.y; w2=u.z; w3=u.w;
    }
    #pragma unroll
    for (int t = 0; t < 4; t++) {
      float tv = tt_lds[j][t];         // LDS broadcast
      a0[t] += tv*w0; a1[t] += tv*w1; a2[t] += tv*w2; a3[t] += tv*w3;
    }
  }

  const int blk = ch0 >> 6, tc = ch0 & 63;
  float inv0 = 0.f, inv1 = 0.f;
  if (do_rope) {
    inv0 = expf(-(float)tc     * (9.210340371976184f/64.0f));   // 2*i0 == tc
    inv1 = expf(-(float)(tc+2) * (9.210340371976184f/64.0f));
  }
  #pragma unroll 2
  for (int t = 0; t < 4; t++) {
    const int rule = rl[t];
    float b0=0.f, b1=0.f, b2=0.f, b3=0.f;
    #pragma unroll
    for (int r = 0; r < 8; r++) {
      float w0,w1,w2,w3;
      if (W_BF) {
        ushort4 u = *(const ushort4*)((const unsigned short*)ro + (size_t)rule*512 + r*64 + tc);
        w0=bf2f(u.x); w1=bf2f(u.y); w2=bf2f(u.z); w3=bf2f(u.w);
      } else {
        float4 u = *(const float4*)((const float*)ro + (size_t)rule*512 + r*64 + tc);
        w0=u.x; w1=u.y; w2=u.z; w3=u.w;
      }
      float hv = hh_lds[t][blk*8 + r];
      b0 += hv*w0; b1 += hv*w1; b2 += hv*w2; b3 += hv*w3;
    }
    float sb = sel[rule*NUM_BLOCKS_ + blk];
    float e0 = a0[t] + b0*sb, o0 = a1[t] + b1*sb;
    float e1 = a2[t] + b2*sb, o1 = a3[t] + b3*sb;
    const int n = n0 + t;
    if (do_rope) {
      float spos = (float)(n & (SS-1));
      float sn0, cs0, sn1, cs1;
      sincosf(spos*inv0, &sn0, &cs0);
      sincosf(spos*inv1, &sn1, &cs1);
      float u0 = e0*cs0 - o0*sn0; o0 = o0*cs0 + e0*sn0; e0 = u0;
      float u1 = e1*cs1 - o1*sn1; o1 = o1*cs1 + e1*sn1; e1 = u1;
    }
    if (out_bf) {
      ushort4 uv; uv.x=f2bf(e0); uv.y=f2bf(o0); uv.z=f2bf(e1); uv.w=f2bf(o1);
      *(ushort4*)((unsigned short*)out + (size_t)n*D_MODEL + ch0) = uv;
    } else {
      float4 fv; fv.x=e0; fv.y=o0; fv.z=e1; fv.w=o1;
      *(float4*)((float*)out + (size_t)n*D_MODEL + ch0) = fv;
    }
  }
}

// Merged dtype dispatch (uniform branch on *flag).
__global__ __launch_bounds__(256) void B_qkv(
    const float* ttg, const float* hhg, const int* rules,
    const void* qso, const void* qro, const void* kso, const void* kro,
    const void* vso, const void* vro,
    const float* sel, float* qb, unsigned short* kb, unsigned short* vb,
    const int* __restrict__ flag)
{
  const int y = blockIdx.y;
  const void* so = (y==0)?qso:((y==1)?kso:vso);
  const void* ro = (y==0)?qro:((y==1)?kro:vro);
  void* out = (y==0)?(void*)qb:((y==1)?(void*)kb:(void*)vb);
  if (*flag)
    stageB_body<true >(ttg, hhg, rules, so, ro, sel + y*1024, out, y, (y<2)?1:0, (y>=1)?1:0);
  else
    stageB_body<false>(ttg, hhg, rules, so, ro, sel + y*1024, out, y, (y<2)?1:0, (y>=1)?1:0);
}

__global__ __launch_bounds__(256) void B_o(
    const float* ttg, const float* hhg, const int* rules,
    const void* oso, const void* oro, const float* sel, void* out,
    const int* __restrict__ flag)
{
  if (*flag) stageB_body<true >(ttg, hhg, rules, oso, oro, sel, out, 0, 0, 1);
  else       stageB_body<false>(ttg, hhg, rules, oso, oro, sel, out, 0, 0, 0);
}

// ---------------------------------------------------------------------------
// Router mask — one 64-thread wave per (b,q); emits the 64-bit allowed-rule
// bitmask + packed per-k-tile rule bytes.
// R8 packing: slot s = g*4+nt (g = key-quad, nt = 16-key tile); byte j of
// slot s = rule of key kt*64 + nt*16 + g*4 + j. The attn kernel (swapped-QK
// layout) loads ONE uint4 per lane: slots [g*4 .. g*4+3] = nt 0..3.
// ---------------------------------------------------------------------------
__global__ __launch_bounds__(64) void mask_kernel(
    const int* __restrict__ rules, const float* __restrict__ M,
    unsigned long long* __restrict__ am, unsigned int* __restrict__ rp)
{
  const int bid = blockIdx.x;              // b*1024 + qi
  const int b = bid >> 10, qi = bid & 1023;
  const int lane = threadIdx.x;
  __shared__ int rrow[SS];
  __shared__ float val[64];
  __shared__ int cnth[64];
  for (int i = lane; i < SS/4; i += 64)
    ((int4*)rrow)[i] = ((const int4*)(rules + b*SS))[i];
  cnth[lane] = 0;
  __syncthreads();                          // rrow + cnth=0 visible
  if (qi < 16 && lane < 16) {               // rule packing (kt = qi)
    const int gg = lane >> 2, nt = lane & 3;
    unsigned v = 0;
    #pragma unroll
    for (int j = 0; j < 4; j++)
      v |= ((unsigned)rrow[qi*64 + nt*16 + gg*4 + j] & 0xffu) << (8*j);
    rp[b*256 + qi*16 + lane] = v;           // lane == gg*4 + nt
  }
  for (int k = lane; k <= qi; k += 64) atomicAdd(&cnth[rrow[k]], 1);
  const int qrule = rrow[qi];
  const float myv = M[qrule*64 + lane];
  val[lane] = myv;
  __syncthreads();                          // histogram + val visible
  const int c = cnth[lane];
  int A = 0;
  for (int r = 0; r < 64; r++) {
    int cr = __shfl(c, r);
    A += (val[r] > myv) ? cr : 0;
  }
  unsigned long long allowed = __ballot(A < 32);  // bit r = rule r allowed
  if (lane == 0) am[bid] = allowed;
}

// ---------------------------------------------------------------------------
// V transpose: vb [n][1024ch] bf16 -> vt [b][h][d][s'] bf16 with the key axis
// PERMUTED inside each 64-key tile by pi(k) = 32*(k>>5) + 8*((k>>2)&3)
// + 4*((k>>4)&1) + (k&3), so the attn PV B-fragment read (chunk kc,g of row
// d) delivers exactly keys (2kc+(j>>2))*16 + 4g + (j&3) — the keys the
// swapped-QK P fragment holds lane-locally. Verified: pi(kappa(kc,g,j)) ==
// 32kc + 8g + j for all (kc,g,j).
// ---------------------------------------------------------------------------
__global__ __launch_bounds__(256) void vtrans_kernel(
    const unsigned short* __restrict__ vb, unsigned short* __restrict__ vt)
{
  const int st = blockIdx.x, h = blockIdx.y, b = blockIdx.z;
  __shared__ unsigned short t[64][72];   // pad 72: 16B-aligned rows
  const int tid = threadIdx.x;
  #pragma unroll
  for (int it = 0; it < 2; it++) {
    int i = tid + it*256;                // 0..511
    int r = i >> 3, c8 = (i & 7)*8;      // token r, channels c8..c8+7
    uint4 v = *(const uint4*)(vb + ((size_t)(b*SS + st*64 + r)*D_MODEL + h*HEAD_DIM + c8));
    t[c8+0][r] = (unsigned short)(v.x & 0xffffu);
    t[c8+1][r] = (unsigned short)(v.x >> 16);
    t[c8+2][r] = (unsigned short)(v.y & 0xffffu);
    t[c8+3][r] = (unsigned short)(v.y >> 16);
    t[c8+4][r] = (unsigned short)(v.z & 0xffffu);
    t[c8+5][r] = (unsigned short)(v.z >> 16);
    t[c8+6][r] = (unsigned short)(v.w & 0xffffu);
    t[c8+7][r] = (unsigned short)(v.w >> 16);
  }
  __syncthreads();
  #pragma unroll
  for (int it = 0; it < 2; it++) {
    int i = tid + it*256;
    int d = i >> 3, c8 = i & 7;          // dim d, key-chunk c8 (keys 8*c8..+7)
    const unsigned short* src = &t[d][c8*8];
    uint2 r1, r2;
    r1.x = (unsigned)src[0] | ((unsigned)src[1] << 16);
    r1.y = (unsigned)src[2] | ((unsigned)src[3] << 16);
    r2.x = (unsigned)src[4] | ((unsigned)src[5] << 16);
    r2.y = (unsigned)src[6] | ((unsigned)src[7] << 16);
    const int base = (c8 >> 2)*32 + 4*((c8 >> 1) & 1);
    const int p1 = base + 8*((2*c8)   & 3);   // pi of keys 8c8..8c8+3
    const int p2 = base + 8*((2*c8+1) & 3);   // pi of keys 8c8+4..8c8+7
    unsigned short* dst = vt + ((size_t)(b*N_HEADS + h)*HEAD_DIM + d)*SS + st*64;
    *(uint2*)(dst + p1) = r1;
    *(uint2*)(dst + p2) = r2;
  }
}

// ---------------------------------------------------------------------------
// Dense masked MFMA flash attention — SWAPPED-QK, P IN REGISTERS (R8).
// R7 counters: all pipes <36% -> still chain/DS-bound; the P LDS round-trip
// (16 ds_write_b16 + 2 ds_read_b128 per wave-step) existed only to transpose
// P between QK-output and PV-A layouts. Fix: compute S = mfma(K, Q) (A/B
// fragment layouts identical -> loads unchanged). Then lane holds P for ONE
// q (= lane&15) and 16 keys {nt*16+4g+r} — the SAME key set for all lanes of
// a group g, which is exactly the MFMA A-operand consistency requirement.
// The lane's own values repack (pure VALU, compile-time idx) into the PV
// A-fragment; V is stored key-permuted (see vtrans pi) so the B-fragment
// read formula is BYTE-IDENTICAL to before. P never touches LDS: -18 DS
// ops/wave-step, Pl deleted (LDS 24->16KB), l is a lane scalar (epilogue
// reduce = 2 shfl). Split-K structure from R6/R7 unchanged.
// ---------------------------------------------------------------------------
__global__ __launch_bounds__(256, 4) void attn_mfma_kernel(
    const float* __restrict__ qb,
    const unsigned short* __restrict__ kb,
    const unsigned short* __restrict__ vtb,
    const unsigned int* __restrict__ rp,
    const unsigned long long* __restrict__ am,
    unsigned short* __restrict__ Obuf,   // fp16 partials [pidx][64][64]
    float* __restrict__ mlbuf,           // [pidx][64]: l per row
    float* outb)
{
  const int x = blockIdx.x, b = blockIdx.y, h = blockIdx.z;
  int qt, k0t, k1t, pidx;
  bool partial;
  if (x < 9) { qt = x; k0t = 0; k1t = qt; partial = false; pidx = 0; }
  else {
    const int j = x - 9, qti = j >> 1, s = j & 1;
    qt = 9 + qti; partial = true;
    pidx = ((b*N_HEADS + h)*7 + qti)*2 + s;
    if (s == 0) { k0t = 0; k1t = 7; } else { k0t = 8; k1t = qt; }
  }
  const int tid = threadIdx.x, lane = tid & 63, w = tid >> 6;
  const int g = lane >> 4, ql = lane & 15;
  __shared__ unsigned short Ks[64*64];      // 8KB swizzled rows [key][d]
  __shared__ unsigned short Vs[64*64];      // 8KB swizzled rows [d][pi(key)]

  const unsigned short* kbase = kb + (size_t)b*SS*D_MODEL + h*HEAD_DIM;
  const unsigned short* vbase = vtb + (size_t)(b*N_HEADS + h)*HEAD_DIM*SS;
  const unsigned int* rpb = rp + b*256;

  const int srow = tid >> 3;    // staging row 0..31 (+32 for second)
  const int spos = tid & 7;     // 16B chunk within 128B row
  // swizzled LDS chunk offset (shorts): byte ≡ (row*128+spos*16)^((row&7)<<4)
  const int sc0 = (srow*8      + (spos ^ (srow      & 7)))*8;
  const int sc1 = ((srow+32)*8 + (spos ^ ((srow+32) & 7)))*8;

  // ---- Q fragment (B-operand: col=q=lane&15, k=d contiguous; x0.125) ----
  const int qa = qt*64 + w*16 + ql;
  bf16x8 qfrag[2];
  {
    const float* qrow = qb + (size_t)(b*SS + qa)*D_MODEL + h*HEAD_DIM + g*8;
    #pragma unroll
    for (int kc = 0; kc < 2; kc++) {
      float4 f0 = *(const float4*)(qrow + kc*32);
      float4 f1 = *(const float4*)(qrow + kc*32 + 4);
      bf16x8 qv;
      qv[0] = (short)f2bf(f0.x*0.125f); qv[1] = (short)f2bf(f0.y*0.125f);
      qv[2] = (short)f2bf(f0.z*0.125f); qv[3] = (short)f2bf(f0.w*0.125f);
      qv[4] = (short)f2bf(f1.x*0.125f); qv[5] = (short)f2bf(f1.y*0.125f);
      qv[6] = (short)f2bf(f1.z*0.125f); qv[7] = (short)f2bf(f1.w*0.125f);
      qfrag[kc] = qv;
    }
  }
  // per-lane single-q allowed mask + causal bound
  const uint2 mm = *(const uint2*)(am + (size_t)b*SS + qa);
  const unsigned aqlo = mm.x, aqhi = mm.y;

  f32x4 Oacc[4];
  #pragma unroll
  for (int nt = 0; nt < 4; nt++) Oacc[nt] = (f32x4){0.f,0.f,0.f,0.f};
  float lrun = 0.f;

  // ---- prologue: stage tile k0t (reg -> swizzled LDS) ----
  {
    const size_t koff0 = (size_t)k0t*64;
    uint4 k0 = *(const uint4*)(kbase + (koff0 + srow)*D_MODEL + spos*8);
    uint4 k1 = *(const uint4*)(kbase + (koff0 + srow + 32)*D_MODEL + spos*8);
    uint4 v0 = *(const uint4*)(vbase + (size_t)srow*SS + koff0 + spos*8);
    uint4 v1 = *(const uint4*)(vbase + (size_t)(srow+32)*SS + koff0 + spos*8);
    *(uint4*)&Ks[sc0] = k0; *(uint4*)&Ks[sc1] = k1;
    *(uint4*)&Vs[sc0] = v0; *(uint4*)&Vs[sc1] = v1;
  }
  __syncthreads();

  for (int kt = k0t; kt <= k1t; kt++) {
    // packed rules: uint4, component nt, byte r -> rule of key kt*64+nt*16+4g+r
    const uint4 ru4 = *(const uint4*)(rpb + kt*16 + g*4);
    // T14: issue next tile's global loads NOW; consumed after the barrier
    uint4 nk0, nk1, nv0, nv1;
    if (kt < k1t) {
      const size_t koff = (size_t)(kt + 1)*64;
      nk0 = *(const uint4*)(kbase + (koff + srow)*D_MODEL + spos*8);
      nk1 = *(const uint4*)(kbase + (koff + srow + 32)*D_MODEL + spos*8);
      nv0 = *(const uint4*)(vbase + (size_t)srow*SS + koff + spos*8);
      nv1 = *(const uint4*)(vbase + (size_t)(srow+32)*SS + koff + spos*8);
    }

    // ---- S = K.Q^T -> D[row=key][col=q]; lane: q=ql, keys nt*16+4g+r ----
    f32x4 Sacc[4];
    __builtin_amdgcn_s_setprio(1);
    #pragma unroll
    for (int nt = 0; nt < 4; nt++) {
      const int key = nt*16 + ql;       // A-operand row
      f32x4 c = (f32x4){0.f,0.f,0.f,0.f};
      #pragma unroll
      for (int kcq = 0; kcq < 2; kcq++) {
        int off = (key*128 + kcq*64 + g*16) ^ ((key & 7) << 4);
        bf16x8 kf = *(const bf16x8*)((const char*)Ks + off);
        c = __builtin_amdgcn_mfma_f32_16x16x32_bf16(kf, qfrag[kcq], c, 0, 0, 0);
      }
      Sacc[nt] = c;
    }
    __builtin_amdgcn_s_setprio(0);

    // ---- mask + fixed-base exp + in-register bf16 pack (no LDS, no shfl) ----
    const bool needc = (kt == qt);
    const unsigned ruarr[4] = {ru4.x, ru4.y, ru4.z, ru4.w};
    unsigned pk[4][2];
    #pragma unroll
    for (int nt = 0; nt < 4; nt++) {
      float p[4];
      #pragma unroll
      for (int r = 0; r < 4; r++) {
        const unsigned rr = (ruarr[nt] >> (8*r)) & 0xffu;
        const unsigned bits = (rr >= 32) ? aqhi : aqlo;
        bool ok = ((bits >> (rr & 31u)) & 1u) != 0u;
        if (needc) ok = ok && ((kt*64 + nt*16 + g*4 + r) <= qa);
        p[r] = __expf(ok ? Sacc[nt][r] : -3e38f);
        lrun += p[r];
      }
      pk[nt][0] = (unsigned)f2bf(p[0]) | ((unsigned)f2bf(p[1]) << 16);
      pk[nt][1] = (unsigned)f2bf(p[2]) | ((unsigned)f2bf(p[3]) << 16);
    }

    // ---- O += P.V: A = lane-local P (keys kappa(kc,g,j)), B = pi-stored V ----
    __builtin_amdgcn_s_setprio(1);
    #pragma unroll
    for (int kc = 0; kc < 2; kc++) {
      union { unsigned u[4]; bf16x8 v; } U;
      U.u[0] = pk[2*kc][0];   U.u[1] = pk[2*kc][1];
      U.u[2] = pk[2*kc+1][0]; U.u[3] = pk[2*kc+1][1];
      const bf16x8 pa = U.v;
      #pragma unroll
      for (int ntd = 0; ntd < 4; ntd++) {
        const int d = ntd*16 + ql;
        int boff = (d*128 + kc*64 + g*16) ^ ((d & 7) << 4);
        bf16x8 vf = *(const bf16x8*)((const char*)Vs + boff);
        Oacc[ntd] = __builtin_amdgcn_mfma_f32_16x16x32_bf16(pa, vf, Oacc[ntd], 0, 0, 0);
      }
    }
    __builtin_amdgcn_s_setprio(0);
    __syncthreads();                 // all waves done reading Ks/Vs
    if (kt < k1t) {                  // write prefetched tile (vmcnt waits here)
      *(uint4*)&Ks[sc0] = nk0; *(uint4*)&Ks[sc1] = nk1;
      *(uint4*)&Vs[sc0] = nv0; *(uint4*)&Vs[sc1] = nv1;
      __syncthreads();               // new tile visible
    }
  }

  // ---- epilogue: reduce l across the 4 key-groups (q = lane&15) ----
  lrun += __shfl_xor(lrun, 16);
  lrun += __shfl_xor(lrun, 32);

  if (!partial) {
    // Oacc rows = q' = g*4+r; l[q'] lives at lane q'
    float invl[4];
    #pragma unroll
    for (int r = 0; r < 4; r++) invl[r] = 1.0f / __shfl(lrun, g*4 + r);
    #pragma unroll
    for (int nt = 0; nt < 4; nt++) {
      #pragma unroll
      for (int r = 0; r < 4; r++) {
        outb[(size_t)(b*SS + qt*64 + w*16 + g*4 + r)*D_MODEL + h*HEAD_DIM + nt*16 + ql]
            = Oacc[nt][r]*invl[r];
      }
    }
  } else {
    // ---- partial: unnormalized O (fp16) + l (fp32); base m == 0 ----
    unsigned short* ob = Obuf + (size_t)pidx*4096;
    #pragma unroll
    for (int nt = 0; nt < 4; nt++) {
      #pragma unroll
      for (int r = 0; r < 4; r++) {
        const int row = w*16 + g*4 + r;
        ob[row*64 + nt*16 + ql] = f2h(Oacc[nt][r]);
      }
    }
    if (lane < 16) mlbuf[(size_t)pidx*64 + w*16 + lane] = lrun;
  }
}

// ---------------------------------------------------------------------------
// Combine the two splits of each (b, h, qt>=9) q-tile. Base m == 0 for both
// splits -> exact merge is (O0 + O1) / (l0 + l1).
// ---------------------------------------------------------------------------
__global__ __launch_bounds__(256) void attn_combine(
    const unsigned short* __restrict__ Obuf, const float* __restrict__ mlbuf,
    float* __restrict__ outb)
{
  const int qti = blockIdx.x, b = blockIdx.y, h = blockIdx.z;
  const int qt = 9 + qti;
  const int p0 = ((b*N_HEADS + h)*7 + qti)*2;
  const int tid = threadIdx.x;
  const int row = tid >> 2, c0 = (tid & 3)*16;
  const float l0 = mlbuf[(size_t)p0*64 + row];
  const float l1 = mlbuf[(size_t)(p0+1)*64 + row];
  const float inv = 1.0f / (l0 + l1);
  const unsigned short* o0 = Obuf + (size_t)p0*4096 + row*64 + c0;
  const unsigned short* o1 = Obuf + (size_t)(p0+1)*4096 + row*64 + c0;
  float* dst = outb + (size_t)(b*SS + qt*64 + row)*D_MODEL + h*HEAD_DIM + c0;
  #pragma unroll
  for (int j = 0; j < 16; j += 4) {
    float4 fv;
    fv.x = (h2f(o0[j+0]) + h2f(o1[j+0]))*inv;
    fv.y = (h2f(o0[j+1]) + h2f(o1[j+1]))*inv;
    fv.z = (h2f(o0[j+2]) + h2f(o1[j+2]))*inv;
    fv.w = (h2f(o0[j+3]) + h2f(o1[j+3]))*inv;
    *(float4*)(dst + j) = fv;
  }
}

// ---------------------------------------------------------------------------
extern "C" void kernel_launch(void* const* d_in, const int* in_sizes, int n_in,
                              void* d_out, int out_size, void* d_ws, size_t ws_size,
                              hipStream_t stream) {
  (void)in_sizes; (void)n_in; (void)out_size; (void)ws_size;
  const void* x    = d_in[0];
  const int* rules = (const int*)d_in[1];
  const void* q_si = d_in[2];  const void* q_so = d_in[3];
  const void* q_ri = d_in[4];  const void* q_ro = d_in[5];  const void* q_lg = d_in[6];
  const void* k_si = d_in[7];  const void* k_so = d_in[8];
  const void* k_ri = d_in[9];  const void* k_ro = d_in[10]; const void* k_lg = d_in[11];
  const void* v_si = d_in[12]; const void* v_so = d_in[13];
  const void* v_ri = d_in[14]; const void* v_ro = d_in[15]; const void* v_lg = d_in[16];
  const void* o_si = d_in[17]; const void* o_so = d_in[18];
  const void* o_ri = d_in[19]; const void* o_ro = d_in[20]; const void* o_lg = d_in[21];
  const void* rq   = d_in[22]; const void* rk   = d_in[23];

  char* ws = (char*)d_ws;
  const size_t MB = 1024*1024;
  float*          qb    = (float*)(ws);                     // 16 MB fp32 (also attn out, in-place)
  unsigned short* kb    = (unsigned short*)(ws + 16*MB);    // 8 MB bf16
  unsigned short* vb    = (unsigned short*)(ws + 24*MB);    // 8 MB bf16
  unsigned short* vtb   = (unsigned short*)(ws + 32*MB);    // 8 MB bf16 V^T [b][h][d][pi(s)]
  float*          ttg   = (float*)(ws + 40*MB);             // 2 MB (dead during attn)
  float*          hhg   = (float*)(ws + 42*MB);             // 6 MB (dead during attn)
  // attn split-K partials: reuse the dead ttg/hhg window [40MB, 48MB)
  unsigned short* Obuf  = (unsigned short*)(ws + 40*MB);    // 896 x 8KB fp16 = 7 MB
  float*          mlbuf = (float*)(ws + 47*MB);             // 896 x 256B
  unsigned long long* amask = (unsigned long long*)(ws + 48*MB); // 32 KB
  float*          Mt    = (float*)(ws + 49*MB + 16*1024);   // 16 KB
  float*          selt  = (float*)(ws + 49*MB + 32*1024);   // 16 KB
  int*            flag  = (int*)  (ws + 49*MB + 48*1024);
  unsigned int*   rp    = (unsigned int*)(ws + 49*MB + 52*1024);  // 4 KB packed rules
  unsigned short* wpkh  = (unsigned short*)(ws + 49*MB + 64*1024);          // 256 KB
  unsigned short* wpkl  = (unsigned short*)(ws + 49*MB + 64*1024 + 256*1024); // 256 KB

  detect_kernel<<<1, 64, 0, stream>>>((const unsigned short*)x, flag);
  precompute_kernel<<<1, 256, 0, stream>>>(rq, rk, q_lg, k_lg, v_lg, o_lg, Mt, selt, flag);
  mask_kernel<<<NTOK, 64, 0, stream>>>(rules, Mt, amask, rp);
  prep_wb_kernel<<<dim3(32, 4), 128, 0, stream>>>(
      (const float*)q_si, (const float*)k_si, (const float*)v_si, (const float*)o_si,
      wpkh, wpkl, flag);

  // QKV stage A
  A_qkv_bf16<<<dim3(NGRP, 3), 256, 0, stream>>>(x, rules, q_si, q_ri, k_si, k_ri, v_si, v_ri, ttg, hhg, flag);
  A_tt_mfma3<<<256, 256, 0, stream>>>((const float*)x, wpkh, wpkl, ttg, flag);
  A_hh3_f32<<<NGRP, 256, 0, stream>>>((const float*)x, rules,
      (const float*)q_ri, (const float*)k_ri, (const float*)v_ri, hhg, flag);

  // Stage B (merged dtype dispatch)
  B_qkv<<<dim3(NGRP4, 3), 256, 0, stream>>>(ttg, hhg, rules, q_so, q_ro, k_so, k_ro, v_so, v_ro,
                                            selt, qb, kb, vb, flag);

  vtrans_kernel<<<dim3(16, 16, 4), 256, 0, stream>>>(vb, vtb);
  attn_mfma_kernel<<<dim3(23, BB, N_HEADS), 256, 0, stream>>>(qb, kb, vtb, rp, amask,
                                                              Obuf, mlbuf, qb);
  attn_combine<<<dim3(7, BB, N_HEADS), 256, 0, stream>>>(Obuf, mlbuf, qb);

  // o-projection: stage A (fp32 input from attn), then stage B to d_out
  // (these overwrite ttg/hhg = the partial buffers, AFTER combine consumed them)
  A_o_bf16<<<dim3(NGRP, 1), 256, 0, stream>>>(qb, rules, o_si, o_ri, ttg, hhg, flag);
  A_tt_mfma1<<<256, 256, 0, stream>>>(qb, wpkh, wpkl, ttg, flag);
  A_hh1_f32<<<NGRP, 256, 0, stream>>>(qb, rules, (const float*)o_ri, hhg, flag);
  B_o<<<NGRP4, 256, 0, stream>>>(ttg, hhg, rules, o_so, o_ro, selt + 3*1024, d_out, flag);
}

// Round 9
// 256.960 us; speedup vs baseline: 1.0578x; 1.0578x over previous
//
#include <hip/hip_runtime.h>
#include <hip/hip_bf16.h>
#include <hip/hip_fp16.h>

#define D_MODEL 1024
#define N_HEADS 16
#define HEAD_DIM 64
#define NUM_RULES 64
#define RANK 8
#define SHARED_RANK 32
#define NUM_BLOCKS_ 16
#define BB 4
#define SS 1024
#define NTOK (BB*SS)
#define NGRP (NTOK/8)
#define NGRP4 (NTOK/4)  // 1024 blocks of 4 tokens (stage B)

typedef __attribute__((ext_vector_type(8))) short bf16x8;   // 8 bf16 = 4 VGPR
typedef __attribute__((ext_vector_type(4))) float f32x4;

__device__ __forceinline__ float bf2f(unsigned short u) {
  unsigned int i = ((unsigned int)u) << 16;
  float f;
  __builtin_memcpy(&f, &i, 4);
  return f;
}
__device__ __forceinline__ unsigned short f2bf(float f) {
  __hip_bfloat16 h = __float2bfloat16(f);
  unsigned short u;
  __builtin_memcpy(&u, &h, 2);
  return u;
}
__device__ __forceinline__ unsigned short f2h(float f) {
  __half h = __float2half(f);
  unsigned short u;
  __builtin_memcpy(&u, &h, 2);
  return u;
}
__device__ __forceinline__ float h2f(unsigned short u) {
  __half h;
  __builtin_memcpy(&h, &u, 2);
  return __half2float(h);
}
template<bool BF>
__device__ __forceinline__ float ldw(const void* p, size_t i) {
  if (BF) return bf2f(((const unsigned short*)p)[i]);
  else    return ((const float*)p)[i];
}

// ---------------------------------------------------------------------------
// Merged dtype detect + precompute (M[64][64], sel[4][64][16]).  R9: one
// launch instead of two; wave 0 detects, LDS flag, all threads run the body.
// ---------------------------------------------------------------------------
template<bool BF>
__device__ __forceinline__ void precompute_body(
    const void* rq, const void* rk,
    const void* qlg, const void* klg, const void* vlg, const void* olg,
    float* __restrict__ M, float* __restrict__ sel)
{
  __shared__ float rqn[64][8], rkn[64][8];
  const int tid = threadIdx.x;  // 256
  if (tid < 64) {
    float v[8]; float s = 0.f;
    for (int i = 0; i < 8; i++) { v[i] = ldw<BF>(rq, tid*8+i); s += v[i]*v[i]; }
    float inv = 1.0f / fmaxf(sqrtf(s), 1e-12f);
    for (int i = 0; i < 8; i++) rqn[tid][i] = v[i]*inv;
  } else if (tid < 128) {
    int r = tid - 64;
    float v[8]; float s = 0.f;
    for (int i = 0; i < 8; i++) { v[i] = ldw<BF>(rk, r*8+i); s += v[i]*v[i]; }
    float inv = 1.0f / fmaxf(sqrtf(s), 1e-12f);
    for (int i = 0; i < 8; i++) rkn[r][i] = v[i]*inv;
  }
  __syncthreads();
  const float LN8 = 2.0794415416798357f;  // 1/tau = ln(8)
  for (int idx = tid; idx < 64*64; idx += 256) {
    int i = idx >> 6, j = idx & 63;
    float d = 0.f;
    for (int t = 0; t < 8; t++) d += rqn[i][t]*rkn[j][t];
    M[idx] = d * LN8;
  }
  const void* lgs[4] = {qlg, klg, vlg, olg};
  {
    int r = tid & 63;
    const void* lg = lgs[tid >> 6];
    float e[NUM_BLOCKS_]; float mx = -1e30f;
    for (int b = 0; b < NUM_BLOCKS_; b++) {
      e[b] = ldw<BF>(lg, r*NUM_BLOCKS_ + b) * 4.0f;
      mx = fmaxf(mx, e[b]);
    }
    float s = 0.f;
    for (int b = 0; b < NUM_BLOCKS_; b++) { e[b] = expf(e[b]-mx); s += e[b]; }
    float inv = 1.0f/s;
    for (int b = 0; b < NUM_BLOCKS_; b++) sel[tid*NUM_BLOCKS_+b] = e[b]*inv;
  }
}

__global__ void detect_precompute_kernel(
    const unsigned short* __restrict__ x, int* __restrict__ flag,
    const void* rq, const void* rk,
    const void* qlg, const void* klg, const void* vlg, const void* olg,
    float* M, float* sel)
{
  __shared__ int fl;
  const int tid = threadIdx.x;
  if (tid < 64) {
    int good = 0;
    for (int i = 0; i < 4; i++) {
      unsigned short u = x[tid*4 + i];
      int e = (u >> 7) & 0xFF;
      good += (e == 0 || (e >= 100 && e <= 145)) ? 1 : 0;
    }
    for (int off = 32; off; off >>= 1) good += __shfl_xor(good, off);
    if (tid == 0) { int g = (good >= 224) ? 1 : 0; flag[0] = g; fl = g; }
  }
  __syncthreads();
  if (fl) precompute_body<true >(rq, rk, qlg, klg, vlg, olg, M, sel);
  else    precompute_body<false>(rq, rk, qlg, klg, vlg, olg, M, sel);
}

// ---------------------------------------------------------------------------
// rope_tab: cs[pos][i0] = (cos, sin)(pos * exp(-2*i0*ln(1e4)/64)).
// Bit-identical to the expressions previously evaluated inside stage B.
// ---------------------------------------------------------------------------
__global__ __launch_bounds__(256) void rope_tab_kernel(float* __restrict__ tab) {
  const int idx = blockIdx.x*256 + threadIdx.x;   // 32768 entries
  const int pos = idx >> 5, i0 = idx & 31;
  float inv = expf(-(float)(2*i0) * (9.210340371976184f/64.0f));
  float sn, cs;
  sincosf((float)pos * inv, &sn, &cs);
  tab[idx*2+0] = cs;
  tab[idx*2+1] = sn;
}

// ---------------------------------------------------------------------------
// prep_wb: pack si (q,k,v,o) into MFMA-B-fragment order, split bf16 hi/lo.
// R9: handles both weight dtypes (runtime flag) — feeds the unified stage A.
// ---------------------------------------------------------------------------
template<bool BF>
__device__ __forceinline__ void prep_wb_body(
    const void* qsi, const void* ksi, const void* vsi, const void* osi,
    unsigned short* __restrict__ wh, unsigned short* __restrict__ wl)
{
  const int kt = blockIdx.x, p = blockIdx.y;
  const int tid = threadIdx.x, nt = tid >> 6, lane = tid & 63;
  const void* si = (p==0)?qsi:((p==1)?ksi:((p==2)?vsi:osi));
  const int col = nt*16 + (lane & 15);
  const int k0 = kt*32 + (lane >> 4)*8;
  size_t base = ((((size_t)p*32 + kt)*2 + nt)*64 + lane)*8;
  unsigned short h8[8], l8[8];
  #pragma unroll
  for (int j = 0; j < 8; j++) {
    float f = ldw<BF>(si, (size_t)(k0 + j)*SHARED_RANK + col);
    unsigned short hu = f2bf(f);
    h8[j] = hu;
    l8[j] = f2bf(f - bf2f(hu));
  }
  #pragma unroll
  for (int j = 0; j < 8; j++) { wh[base + j] = h8[j]; wl[base + j] = l8[j]; }
}

__global__ __launch_bounds__(128) void prep_wb_kernel(
    const void* qsi, const void* ksi, const void* vsi, const void* osi,
    unsigned short* wh, unsigned short* wl, const int* __restrict__ flag)
{
  if (*flag) prep_wb_body<true >(qsi, ksi, vsi, osi, wh, wl);
  else       prep_wb_body<false>(qsi, ksi, vsi, osi, wh, wl);
}

// ---------------------------------------------------------------------------
// A_tt_mfma: tt[y][n][32] = x @ si via split-bf16 MFMA (3 passes).
// R9: x dtype is a template param (runtime flag dispatch) — bf16-input path
// routes here too; the old fused stageA (and its dead launches) is deleted.
// ---------------------------------------------------------------------------
template<bool IN_BF, int NPROJ>
__device__ __forceinline__ void tt_mfma_body(
    const void* __restrict__ xin,
    const unsigned short* __restrict__ wh, const unsigned short* __restrict__ wl,
    int p0, float* __restrict__ ttg)
{
  const int NT = NPROJ*2;
  const int tile = blockIdx.x;          // 16-token tile
  const int tid = threadIdx.x, lane = tid & 63, w = tid >> 6;
  const int kq = lane >> 4;
  __shared__ float red[4][64][25];      // pad 25: conflict-free reduce

  f32x4 acc[NT];
  #pragma unroll
  for (int i = 0; i < NT; i++) acc[i] = (f32x4){0.f,0.f,0.f,0.f};

  const size_t rowoff = (size_t)(tile*16 + (lane & 15))*D_MODEL + kq*8;
  #pragma unroll 2
  for (int s = 0; s < 8; s++) {
    const int kt = w*8 + s;
    float av[8];
    if (IN_BF) {
      const unsigned short* xr = (const unsigned short*)xin + rowoff + kt*32;
      ushort4 u0 = *(const ushort4*)(xr);
      ushort4 u1 = *(const ushort4*)(xr + 4);
      av[0]=bf2f(u0.x); av[1]=bf2f(u0.y); av[2]=bf2f(u0.z); av[3]=bf2f(u0.w);
      av[4]=bf2f(u1.x); av[5]=bf2f(u1.y); av[6]=bf2f(u1.z); av[7]=bf2f(u1.w);
    } else {
      const float* xr = (const float*)xin + rowoff + kt*32;
      float4 a0 = *(const float4*)(xr);
      float4 a1 = *(const float4*)(xr + 4);
      av[0]=a0.x; av[1]=a0.y; av[2]=a0.z; av[3]=a0.w;
      av[4]=a1.x; av[5]=a1.y; av[6]=a1.z; av[7]=a1.w;
    }
    bf16x8 ah, al;
    #pragma unroll
    for (int j = 0; j < 8; j++) {
      unsigned short hu = f2bf(av[j]);
      ah[j] = (short)hu;
      al[j] = (short)f2bf(av[j] - bf2f(hu));
    }
    #pragma unroll
    for (int p = 0; p < NPROJ; p++) {
      #pragma unroll
      for (int nt = 0; nt < 2; nt++) {
        size_t bidx = ((((size_t)(p0+p)*32 + kt)*2 + nt)*64 + lane)*8;
        bf16x8 bh = *(const bf16x8*)(wh + bidx);
        bf16x8 bl = *(const bf16x8*)(wl + bidx);
        f32x4 c = acc[p*2+nt];
        c = __builtin_amdgcn_mfma_f32_16x16x32_bf16(ah, bh, c, 0, 0, 0);
        c = __builtin_amdgcn_mfma_f32_16x16x32_bf16(al, bh, c, 0, 0, 0);
        c = __builtin_amdgcn_mfma_f32_16x16x32_bf16(ah, bl, c, 0, 0, 0);
        acc[p*2+nt] = c;
      }
    }
  }
  #pragma unroll
  for (int i = 0; i < NT; i++) {
    red[w][lane][i*4+0] = acc[i][0]; red[w][lane][i*4+1] = acc[i][1];
    red[w][lane][i*4+2] = acc[i][2]; red[w][lane][i*4+3] = acc[i][3];
  }
  __syncthreads();
  if (w == 0) {
    const int tok0 = tile*16 + (lane >> 4)*4;   // C/D: row=(lane>>4)*4+r
    #pragma unroll
    for (int i = 0; i < NT; i++) {
      const int ys = i >> 1, jj = (i & 1)*16 + (lane & 15);
      #pragma unroll
      for (int r = 0; r < 4; r++) {
        float sum = red[0][lane][i*4+r] + red[1][lane][i*4+r]
                  + red[2][lane][i*4+r] + red[3][lane][i*4+r];
        ttg[((size_t)ys*NTOK + tok0 + r)*32 + jj] = sum;
      }
    }
  }
}

__global__ __launch_bounds__(256) void A_tt_mfma3(
    const void* __restrict__ xin,
    const unsigned short* __restrict__ wh, const unsigned short* __restrict__ wl,
    float* __restrict__ ttg, const int* __restrict__ flag)
{
  if (*flag) tt_mfma_body<true, 3>(xin, wh, wl, 0, ttg);
  else       tt_mfma_body<false,3>(xin, wh, wl, 0, ttg);
}

__global__ __launch_bounds__(256) void A_tt_mfma1(
    const void* __restrict__ xin,
    const unsigned short* __restrict__ wh, const unsigned short* __restrict__ wl,
    float* __restrict__ ttg, const int* __restrict__ flag)
{
  (void)flag;  // input (attn out) is always fp32
  tt_mfma_body<false,1>(xin, wh, wl, 3, ttg);
}

// ---------------------------------------------------------------------------
// A_hh: low-rank inner hh[y][n][16][8], LDS-free, q/k/v fused.
// R9: dtype-templated (x and ri), runtime flag dispatch.
// ---------------------------------------------------------------------------
template<bool IN_BF, bool W_BF, int NP>
__device__ __forceinline__ void hh_body(
    const void* __restrict__ xin, const int* __restrict__ rules,
    const void* __restrict__ ri0, const void* __restrict__ ri1,
    const void* __restrict__ ri2, float* __restrict__ hhg)
{
  const int g = blockIdx.x, n0 = g*8, tid = threadIdx.x;
  const int t = tid >> 5, blk = (tid >> 1) & 15, r0 = (tid & 1)*4;
  const int n = n0 + t;
  const int rule = rules[n];
  const size_t xoff = (size_t)n*D_MODEL + blk*64;
  const void* wb[3];
  wb[0] = ri0;
  if (NP > 1) { wb[1] = ri1; wb[2] = ri2; }
  float a[NP][4];
  #pragma unroll
  for (int p = 0; p < NP; p++) { a[p][0]=0.f; a[p][1]=0.f; a[p][2]=0.f; a[p][3]=0.f; }
  #pragma unroll 4
  for (int k4 = 0; k4 < 16; k4++) {
    float xv[4];
    if (IN_BF) {
      ushort4 u = *(const ushort4*)((const unsigned short*)xin + xoff + k4*4);
      xv[0]=bf2f(u.x); xv[1]=bf2f(u.y); xv[2]=bf2f(u.z); xv[3]=bf2f(u.w);
    } else {
      float4 u = *(const float4*)((const float*)xin + xoff + k4*4);
      xv[0]=u.x; xv[1]=u.y; xv[2]=u.z; xv[3]=u.w;
    }
    #pragma unroll
    for (int q = 0; q < 4; q++) {
      const int k = k4*4 + q;
      const float xq = xv[q];
      #pragma unroll
      for (int p = 0; p < NP; p++) {
        float w0,w1,w2,w3;
        if (W_BF) {
          ushort4 u = *(const ushort4*)((const unsigned short*)wb[p] + (size_t)rule*512 + (size_t)k*8 + r0);
          w0=bf2f(u.x); w1=bf2f(u.y); w2=bf2f(u.z); w3=bf2f(u.w);
        } else {
          float4 u = *(const float4*)((const float*)wb[p] + (size_t)rule*512 + (size_t)k*8 + r0);
          w0=u.x; w1=u.y; w2=u.z; w3=u.w;
        }
        a[p][0] += xq*w0; a[p][1] += xq*w1; a[p][2] += xq*w2; a[p][3] += xq*w3;
      }
    }
  }
  #pragma unroll
  for (int p = 0; p < NP; p++) {
    float4 hv; hv.x=a[p][0]; hv.y=a[p][1]; hv.z=a[p][2]; hv.w=a[p][3];
    *(float4*)&hhg[((size_t)p*NTOK + n)*128 + blk*8 + r0] = hv;
  }
}

__global__ __launch_bounds__(256) void A_hh3(
    const void* __restrict__ xin, const int* __restrict__ rules,
    const void* __restrict__ qri, const void* __restrict__ kri,
    const void* __restrict__ vri, float* __restrict__ hhg,
    const int* __restrict__ flag)
{
  if (*flag) hh_body<true, true, 3>(xin, rules, qri, kri, vri, hhg);
  else       hh_body<false,false,3>(xin, rules, qri, kri, vri, hhg);
}

__global__ __launch_bounds__(256) void A_hh1(
    const void* __restrict__ xin, const int* __restrict__ rules,
    const void* __restrict__ ori, float* __restrict__ hhg,
    const int* __restrict__ flag)
{
  if (*flag) hh_body<false,true, 1>(xin, rules, ori, ori, ori, hhg);
  else       hh_body<false,false,1>(xin, rules, ori, ori, ori, hhg);
}

// ---------------------------------------------------------------------------
// Stage B: 4 tokens/block. R9: rope via precomputed table (bit-identical).
// ---------------------------------------------------------------------------
template<bool W_BF>
__device__ __forceinline__ void stageB_body(
    const float* __restrict__ ttg, const float* __restrict__ hhg,
    const int* __restrict__ rules,
    const void* __restrict__ so, const void* __restrict__ ro,
    const float* __restrict__ sel, const float* __restrict__ ropet,
    void* __restrict__ out,
    int yslot, int do_rope, int out_bf)
{
  const int blk4 = blockIdx.x;            // 4-token block
  const int n0 = blk4*4, tid = threadIdx.x;
  __shared__ float tt_lds[32][5];    // [j][t4], pad 5
  __shared__ float hh_lds[4][132];   // [t4][blk*8+r]
  __shared__ int rl[4];

  if (tid < 128) {                    // tt: 32 j x 4 tokens
    const int j = tid >> 2, t4 = tid & 3;
    tt_lds[j][t4] = ttg[((size_t)yslot*NTOK + n0 + t4)*32 + j];
  } else if (tid < 256 && (tid - 128) < 128) {  // hh: 4 tokens x 128 floats
    const int i = tid - 128;
    const int t4 = i >> 5, c = (i*4) & 127;
    float4 hv = *(const float4*)&hhg[((size_t)yslot*NTOK + n0 + t4)*128 + c];
    *(float4*)&hh_lds[t4][c] = hv;
  }
  if (tid < 4) rl[tid] = rules[n0 + tid];
  __syncthreads();

  const int ch0 = tid*4;
  float a0[4], a1[4], a2[4], a3[4];
  #pragma unroll
  for (int t = 0; t < 4; t++) { a0[t]=0.f; a1[t]=0.f; a2[t]=0.f; a3[t]=0.f; }

  #pragma unroll 4
  for (int j = 0; j < 32; j++) {
    float w0, w1, w2, w3;
    if (W_BF) {
      ushort4 u = *(const ushort4*)((const unsigned short*)so + (size_t)j*D_MODEL + ch0);
      w0=bf2f(u.x); w1=bf2f(u.y); w2=bf2f(u.z); w3=bf2f(u.w);
    } else {
      float4 u = *(const float4*)((const float*)so + (size_t)j*D_MODEL + ch0);
      w0=u.x; w1=u.y; w2=u.z; w3=u.w;
    }
    #pragma unroll
    for (int t = 0; t < 4; t++) {
      float tv = tt_lds[j][t];         // LDS broadcast
      a0[t] += tv*w0; a1[t] += tv*w1; a2[t] += tv*w2; a3[t] += tv*w3;
    }
  }

  const int blk = ch0 >> 6, tc = ch0 & 63;
  #pragma unroll 2
  for (int t = 0; t < 4; t++) {
    const int rule = rl[t];
    float b0=0.f, b1=0.f, b2=0.f, b3=0.f;
    #pragma unroll
    for (int r = 0; r < 8; r++) {
      float w0,w1,w2,w3;
      if (W_BF) {
        ushort4 u = *(const ushort4*)((const unsigned short*)ro + (size_t)rule*512 + r*64 + tc);
        w0=bf2f(u.x); w1=bf2f(u.y); w2=bf2f(u.z); w3=bf2f(u.w);
      } else {
        float4 u = *(const float4*)((const float*)ro + (size_t)rule*512 + r*64 + tc);
        w0=u.x; w1=u.y; w2=u.z; w3=u.w;
      }
      float hv = hh_lds[t][blk*8 + r];
      b0 += hv*w0; b1 += hv*w1; b2 += hv*w2; b3 += hv*w3;
    }
    float sb = sel[rule*NUM_BLOCKS_ + blk];
    float e0 = a0[t] + b0*sb, o0 = a1[t] + b1*sb;
    float e1 = a2[t] + b2*sb, o1 = a3[t] + b3*sb;
    const int n = n0 + t;
    if (do_rope) {
      // table: cs[pos][i0] pairs; i0 = tc/2 and tc/2+1 -> one float4
      float4 cs = *(const float4*)(ropet + ((size_t)(n & (SS-1))*32 + (tc >> 1))*2);
      float u0 = e0*cs.x - o0*cs.y; o0 = o0*cs.x + e0*cs.y; e0 = u0;
      float u1 = e1*cs.z - o1*cs.w; o1 = o1*cs.z + e1*cs.w; e1 = u1;
    }
    if (out_bf) {
      ushort4 uv; uv.x=f2bf(e0); uv.y=f2bf(o0); uv.z=f2bf(e1); uv.w=f2bf(o1);
      *(ushort4*)((unsigned short*)out + (size_t)n*D_MODEL + ch0) = uv;
    } else {
      float4 fv; fv.x=e0; fv.y=o0; fv.z=e1; fv.w=o1;
      *(float4*)((float*)out + (size_t)n*D_MODEL + ch0) = fv;
    }
  }
}

// Merged dtype dispatch (uniform branch on *flag).
__global__ __launch_bounds__(256) void B_qkv(
    const float* ttg, const float* hhg, const int* rules,
    const void* qso, const void* qro, const void* kso, const void* kro,
    const void* vso, const void* vro,
    const float* sel, const float* ropet,
    float* qb, unsigned short* kb, unsigned short* vb,
    const int* __restrict__ flag)
{
  const int y = blockIdx.y;
  const void* so = (y==0)?qso:((y==1)?kso:vso);
  const void* ro = (y==0)?qro:((y==1)?kro:vro);
  void* out = (y==0)?(void*)qb:((y==1)?(void*)kb:(void*)vb);
  if (*flag)
    stageB_body<true >(ttg, hhg, rules, so, ro, sel + y*1024, ropet, out, y, (y<2)?1:0, (y>=1)?1:0);
  else
    stageB_body<false>(ttg, hhg, rules, so, ro, sel + y*1024, ropet, out, y, (y<2)?1:0, (y>=1)?1:0);
}

__global__ __launch_bounds__(256) void B_o(
    const float* ttg, const float* hhg, const int* rules,
    const void* oso, const void* oro, const float* sel, const float* ropet,
    void* out, const int* __restrict__ flag)
{
  if (*flag) stageB_body<true >(ttg, hhg, rules, oso, oro, sel, ropet, out, 0, 0, 1);
  else       stageB_body<false>(ttg, hhg, rules, oso, oro, sel, ropet, out, 0, 0, 0);
}

// ---------------------------------------------------------------------------
// Router mask — one 64-thread wave per (b,q); emits the 64-bit allowed-rule
// bitmask + packed per-k-tile rule bytes (R8 layout: slot s = g*4+nt, byte j
// = rule of key kt*64 + nt*16 + g*4 + j).
// ---------------------------------------------------------------------------
__global__ __launch_bounds__(64) void mask_kernel(
    const int* __restrict__ rules, const float* __restrict__ M,
    unsigned long long* __restrict__ am, unsigned int* __restrict__ rp)
{
  const int bid = blockIdx.x;              // b*1024 + qi
  const int b = bid >> 10, qi = bid & 1023;
  const int lane = threadIdx.x;
  __shared__ int rrow[SS];
  __shared__ float val[64];
  __shared__ int cnth[64];
  for (int i = lane; i < SS/4; i += 64)
    ((int4*)rrow)[i] = ((const int4*)(rules + b*SS))[i];
  cnth[lane] = 0;
  __syncthreads();                          // rrow + cnth=0 visible
  if (qi < 16 && lane < 16) {               // rule packing (kt = qi)
    const int gg = lane >> 2, nt = lane & 3;
    unsigned v = 0;
    #pragma unroll
    for (int j = 0; j < 4; j++)
      v |= ((unsigned)rrow[qi*64 + nt*16 + gg*4 + j] & 0xffu) << (8*j);
    rp[b*256 + qi*16 + lane] = v;           // lane == gg*4 + nt
  }
  for (int k = lane; k <= qi; k += 64) atomicAdd(&cnth[rrow[k]], 1);
  const int qrule = rrow[qi];
  const float myv = M[qrule*64 + lane];
  val[lane] = myv;
  __syncthreads();                          // histogram + val visible
  const int c = cnth[lane];
  int A = 0;
  for (int r = 0; r < 64; r++) {
    int cr = __shfl(c, r);
    A += (val[r] > myv) ? cr : 0;
  }
  unsigned long long allowed = __ballot(A < 32);  // bit r = rule r allowed
  if (lane == 0) am[bid] = allowed;
}

// ---------------------------------------------------------------------------
// V transpose: vb [n][1024ch] bf16 -> vt [b][h][d][s'] bf16, key axis
// permuted inside each 64-key tile by pi(k) = 32*(k>>5) + 8*((k>>2)&3)
// + 4*((k>>4)&1) + (k&3) to match the swapped-QK lane-local P layout.
// ---------------------------------------------------------------------------
__global__ __launch_bounds__(256) void vtrans_kernel(
    const unsigned short* __restrict__ vb, unsigned short* __restrict__ vt)
{
  const int st = blockIdx.x, h = blockIdx.y, b = blockIdx.z;
  __shared__ unsigned short t[64][72];   // pad 72: 16B-aligned rows
  const int tid = threadIdx.x;
  #pragma unroll
  for (int it = 0; it < 2; it++) {
    int i = tid + it*256;                // 0..511
    int r = i >> 3, c8 = (i & 7)*8;      // token r, channels c8..c8+7
    uint4 v = *(const uint4*)(vb + ((size_t)(b*SS + st*64 + r)*D_MODEL + h*HEAD_DIM + c8));
    t[c8+0][r] = (unsigned short)(v.x & 0xffffu);
    t[c8+1][r] = (unsigned short)(v.x >> 16);
    t[c8+2][r] = (unsigned short)(v.y & 0xffffu);
    t[c8+3][r] = (unsigned short)(v.y >> 16);
    t[c8+4][r] = (unsigned short)(v.z & 0xffffu);
    t[c8+5][r] = (unsigned short)(v.z >> 16);
    t[c8+6][r] = (unsigned short)(v.w & 0xffffu);
    t[c8+7][r] = (unsigned short)(v.w >> 16);
  }
  __syncthreads();
  #pragma unroll
  for (int it = 0; it < 2; it++) {
    int i = tid + it*256;
    int d = i >> 3, c8 = i & 7;          // dim d, key-chunk c8 (keys 8*c8..+7)
    const unsigned short* src = &t[d][c8*8];
    uint2 r1, r2;
    r1.x = (unsigned)src[0] | ((unsigned)src[1] << 16);
    r1.y = (unsigned)src[2] | ((unsigned)src[3] << 16);
    r2.x = (unsigned)src[4] | ((unsigned)src[5] << 16);
    r2.y = (unsigned)src[6] | ((unsigned)src[7] << 16);
    const int base = (c8 >> 2)*32 + 4*((c8 >> 1) & 1);
    const int p1 = base + 8*((2*c8)   & 3);   // pi of keys 8c8..8c8+3
    const int p2 = base + 8*((2*c8+1) & 3);   // pi of keys 8c8+4..8c8+7
    unsigned short* dst = vt + ((size_t)(b*N_HEADS + h)*HEAD_DIM + d)*SS + st*64;
    *(uint2*)(dst + p1) = r1;
    *(uint2*)(dst + p2) = r2;
  }
}

// ---------------------------------------------------------------------------
// Dense masked MFMA flash attention — swapped-QK, P in registers, split-K,
// fixed-base softmax (unchanged from R8).
// ---------------------------------------------------------------------------
__global__ __launch_bounds__(256, 4) void attn_mfma_kernel(
    const float* __restrict__ qb,
    const unsigned short* __restrict__ kb,
    const unsigned short* __restrict__ vtb,
    const unsigned int* __restrict__ rp,
    const unsigned long long* __restrict__ am,
    unsigned short* __restrict__ Obuf,   // fp16 partials [pidx][64][64]
    float* __restrict__ mlbuf,           // [pidx][64]: l per row
    float* outb)
{
  const int x = blockIdx.x, b = blockIdx.y, h = blockIdx.z;
  int qt, k0t, k1t, pidx;
  bool partial;
  if (x < 9) { qt = x; k0t = 0; k1t = qt; partial = false; pidx = 0; }
  else {
    const int j = x - 9, qti = j >> 1, s = j & 1;
    qt = 9 + qti; partial = true;
    pidx = ((b*N_HEADS + h)*7 + qti)*2 + s;
    if (s == 0) { k0t = 0; k1t = 7; } else { k0t = 8; k1t = qt; }
  }
  const int tid = threadIdx.x, lane = tid & 63, w = tid >> 6;
  const int g = lane >> 4, ql = lane & 15;
  __shared__ unsigned short Ks[64*64];      // 8KB swizzled rows [key][d]
  __shared__ unsigned short Vs[64*64];      // 8KB swizzled rows [d][pi(key)]

  const unsigned short* kbase = kb + (size_t)b*SS*D_MODEL + h*HEAD_DIM;
  const unsigned short* vbase = vtb + (size_t)(b*N_HEADS + h)*HEAD_DIM*SS;
  const unsigned int* rpb = rp + b*256;

  const int srow = tid >> 3;    // staging row 0..31 (+32 for second)
  const int spos = tid & 7;     // 16B chunk within 128B row
  const int sc0 = (srow*8      + (spos ^ (srow      & 7)))*8;
  const int sc1 = ((srow+32)*8 + (spos ^ ((srow+32) & 7)))*8;

  // ---- Q fragment (B-operand: col=q=lane&15, k=d contiguous; x0.125) ----
  const int qa = qt*64 + w*16 + ql;
  bf16x8 qfrag[2];
  {
    const float* qrow = qb + (size_t)(b*SS + qa)*D_MODEL + h*HEAD_DIM + g*8;
    #pragma unroll
    for (int kc = 0; kc < 2; kc++) {
      float4 f0 = *(const float4*)(qrow + kc*32);
      float4 f1 = *(const float4*)(qrow + kc*32 + 4);
      bf16x8 qv;
      qv[0] = (short)f2bf(f0.x*0.125f); qv[1] = (short)f2bf(f0.y*0.125f);
      qv[2] = (short)f2bf(f0.z*0.125f); qv[3] = (short)f2bf(f0.w*0.125f);
      qv[4] = (short)f2bf(f1.x*0.125f); qv[5] = (short)f2bf(f1.y*0.125f);
      qv[6] = (short)f2bf(f1.z*0.125f); qv[7] = (short)f2bf(f1.w*0.125f);
      qfrag[kc] = qv;
    }
  }
  const uint2 mm = *(const uint2*)(am + (size_t)b*SS + qa);
  const unsigned aqlo = mm.x, aqhi = mm.y;

  f32x4 Oacc[4];
  #pragma unroll
  for (int nt = 0; nt < 4; nt++) Oacc[nt] = (f32x4){0.f,0.f,0.f,0.f};
  float lrun = 0.f;

  // ---- prologue: stage tile k0t (reg -> swizzled LDS) ----
  {
    const size_t koff0 = (size_t)k0t*64;
    uint4 k0 = *(const uint4*)(kbase + (koff0 + srow)*D_MODEL + spos*8);
    uint4 k1 = *(const uint4*)(kbase + (koff0 + srow + 32)*D_MODEL + spos*8);
    uint4 v0 = *(const uint4*)(vbase + (size_t)srow*SS + koff0 + spos*8);
    uint4 v1 = *(const uint4*)(vbase + (size_t)(srow+32)*SS + koff0 + spos*8);
    *(uint4*)&Ks[sc0] = k0; *(uint4*)&Ks[sc1] = k1;
    *(uint4*)&Vs[sc0] = v0; *(uint4*)&Vs[sc1] = v1;
  }
  __syncthreads();

  for (int kt = k0t; kt <= k1t; kt++) {
    const uint4 ru4 = *(const uint4*)(rpb + kt*16 + g*4);
    uint4 nk0, nk1, nv0, nv1;
    if (kt < k1t) {
      const size_t koff = (size_t)(kt + 1)*64;
      nk0 = *(const uint4*)(kbase + (koff + srow)*D_MODEL + spos*8);
      nk1 = *(const uint4*)(kbase + (koff + srow + 32)*D_MODEL + spos*8);
      nv0 = *(const uint4*)(vbase + (size_t)srow*SS + koff + spos*8);
      nv1 = *(const uint4*)(vbase + (size_t)(srow+32)*SS + koff + spos*8);
    }

    // ---- S = K.Q^T -> D[row=key][col=q]; lane: q=ql, keys nt*16+4g+r ----
    f32x4 Sacc[4];
    __builtin_amdgcn_s_setprio(1);
    #pragma unroll
    for (int nt = 0; nt < 4; nt++) {
      const int key = nt*16 + ql;       // A-operand row
      f32x4 c = (f32x4){0.f,0.f,0.f,0.f};
      #pragma unroll
      for (int kcq = 0; kcq < 2; kcq++) {
        int off = (key*128 + kcq*64 + g*16) ^ ((key & 7) << 4);
        bf16x8 kf = *(const bf16x8*)((const char*)Ks + off);
        c = __builtin_amdgcn_mfma_f32_16x16x32_bf16(kf, qfrag[kcq], c, 0, 0, 0);
      }
      Sacc[nt] = c;
    }
    __builtin_amdgcn_s_setprio(0);

    // ---- mask + fixed-base exp + in-register bf16 pack ----
    const bool needc = (kt == qt);
    const unsigned ruarr[4] = {ru4.x, ru4.y, ru4.z, ru4.w};
    unsigned pk[4][2];
    #pragma unroll
    for (int nt = 0; nt < 4; nt++) {
      float p[4];
      #pragma unroll
      for (int r = 0; r < 4; r++) {
        const unsigned rr = (ruarr[nt] >> (8*r)) & 0xffu;
        const unsigned bits = (rr >= 32) ? aqhi : aqlo;
        bool ok = ((bits >> (rr & 31u)) & 1u) != 0u;
        if (needc) ok = ok && ((kt*64 + nt*16 + g*4 + r) <= qa);
        p[r] = __expf(ok ? Sacc[nt][r] : -3e38f);
        lrun += p[r];
      }
      pk[nt][0] = (unsigned)f2bf(p[0]) | ((unsigned)f2bf(p[1]) << 16);
      pk[nt][1] = (unsigned)f2bf(p[2]) | ((unsigned)f2bf(p[3]) << 16);
    }

    // ---- O += P.V: A = lane-local P, B = pi-stored V ----
    __builtin_amdgcn_s_setprio(1);
    #pragma unroll
    for (int kc = 0; kc < 2; kc++) {
      union { unsigned u[4]; bf16x8 v; } U;
      U.u[0] = pk[2*kc][0];   U.u[1] = pk[2*kc][1];
      U.u[2] = pk[2*kc+1][0]; U.u[3] = pk[2*kc+1][1];
      const bf16x8 pa = U.v;
      #pragma unroll
      for (int ntd = 0; ntd < 4; ntd++) {
        const int d = ntd*16 + ql;
        int boff = (d*128 + kc*64 + g*16) ^ ((d & 7) << 4);
        bf16x8 vf = *(const bf16x8*)((const char*)Vs + boff);
        Oacc[ntd] = __builtin_amdgcn_mfma_f32_16x16x32_bf16(pa, vf, Oacc[ntd], 0, 0, 0);
      }
    }
    __builtin_amdgcn_s_setprio(0);
    __syncthreads();                 // all waves done reading Ks/Vs
    if (kt < k1t) {                  // write prefetched tile (vmcnt waits here)
      *(uint4*)&Ks[sc0] = nk0; *(uint4*)&Ks[sc1] = nk1;
      *(uint4*)&Vs[sc0] = nv0; *(uint4*)&Vs[sc1] = nv1;
      __syncthreads();               // new tile visible
    }
  }

  // ---- epilogue: reduce l across the 4 key-groups (q = lane&15) ----
  lrun += __shfl_xor(lrun, 16);
  lrun += __shfl_xor(lrun, 32);

  if (!partial) {
    float invl[4];
    #pragma unroll
    for (int r = 0; r < 4; r++) invl[r] = 1.0f / __shfl(lrun, g*4 + r);
    #pragma unroll
    for (int nt = 0; nt < 4; nt++) {
      #pragma unroll
      for (int r = 0; r < 4; r++) {
        outb[(size_t)(b*SS + qt*64 + w*16 + g*4 + r)*D_MODEL + h*HEAD_DIM + nt*16 + ql]
            = Oacc[nt][r]*invl[r];
      }
    }
  } else {
    unsigned short* ob = Obuf + (size_t)pidx*4096;
    #pragma unroll
    for (int nt = 0; nt < 4; nt++) {
      #pragma unroll
      for (int r = 0; r < 4; r++) {
        const int row = w*16 + g*4 + r;
        ob[row*64 + nt*16 + ql] = f2h(Oacc[nt][r]);
      }
    }
    if (lane < 16) mlbuf[(size_t)pidx*64 + w*16 + lane] = lrun;
  }
}

// ---------------------------------------------------------------------------
// Combine the two splits of each (b, h, qt>=9) q-tile: (O0+O1)/(l0+l1).
// ---------------------------------------------------------------------------
__global__ __launch_bounds__(256) void attn_combine(
    const unsigned short* __restrict__ Obuf, const float* __restrict__ mlbuf,
    float* __restrict__ outb)
{
  const int qti = blockIdx.x, b = blockIdx.y, h = blockIdx.z;
  const int qt = 9 + qti;
  const int p0 = ((b*N_HEADS + h)*7 + qti)*2;
  const int tid = threadIdx.x;
  const int row = tid >> 2, c0 = (tid & 3)*16;
  const float l0 = mlbuf[(size_t)p0*64 + row];
  const float l1 = mlbuf[(size_t)(p0+1)*64 + row];
  const float inv = 1.0f / (l0 + l1);
  const unsigned short* o0 = Obuf + (size_t)p0*4096 + row*64 + c0;
  const unsigned short* o1 = Obuf + (size_t)(p0+1)*4096 + row*64 + c0;
  float* dst = outb + (size_t)(b*SS + qt*64 + row)*D_MODEL + h*HEAD_DIM + c0;
  #pragma unroll
  for (int j = 0; j < 16; j += 4) {
    float4 fv;
    fv.x = (h2f(o0[j+0]) + h2f(o1[j+0]))*inv;
    fv.y = (h2f(o0[j+1]) + h2f(o1[j+1]))*inv;
    fv.z = (h2f(o0[j+2]) + h2f(o1[j+2]))*inv;
    fv.w = (h2f(o0[j+3]) + h2f(o1[j+3]))*inv;
    *(float4*)(dst + j) = fv;
  }
}

// ---------------------------------------------------------------------------
extern "C" void kernel_launch(void* const* d_in, const int* in_sizes, int n_in,
                              void* d_out, int out_size, void* d_ws, size_t ws_size,
                              hipStream_t stream) {
  (void)in_sizes; (void)n_in; (void)out_size; (void)ws_size;
  const void* x    = d_in[0];
  const int* rules = (const int*)d_in[1];
  const void* q_si = d_in[2];  const void* q_so = d_in[3];
  const void* q_ri = d_in[4];  const void* q_ro = d_in[5];  const void* q_lg = d_in[6];
  const void* k_si = d_in[7];  const void* k_so = d_in[8];
  const void* k_ri = d_in[9];  const void* k_ro = d_in[10]; const void* k_lg = d_in[11];
  const void* v_si = d_in[12]; const void* v_so = d_in[13];
  const void* v_ri = d_in[14]; const void* v_ro = d_in[15]; const void* v_lg = d_in[16];
  const void* o_si = d_in[17]; const void* o_so = d_in[18];
  const void* o_ri = d_in[19]; const void* o_ro = d_in[20]; const void* o_lg = d_in[21];
  const void* rq   = d_in[22]; const void* rk   = d_in[23];

  char* ws = (char*)d_ws;
  const size_t MB = 1024*1024;
  float*          qb    = (float*)(ws);                     // 16 MB fp32 (also attn out, in-place)
  unsigned short* kb    = (unsigned short*)(ws + 16*MB);    // 8 MB bf16
  unsigned short* vb    = (unsigned short*)(ws + 24*MB);    // 8 MB bf16
  unsigned short* vtb   = (unsigned short*)(ws + 32*MB);    // 8 MB bf16 V^T [b][h][d][pi(s)]
  float*          ttg   = (float*)(ws + 40*MB);             // 2 MB (dead during attn)
  float*          hhg   = (float*)(ws + 42*MB);             // 6 MB (dead during attn)
  // attn split-K partials: reuse the dead ttg/hhg window [40MB, 48MB)
  unsigned short* Obuf  = (unsigned short*)(ws + 40*MB);    // 896 x 8KB fp16 = 7 MB
  float*          mlbuf = (float*)(ws + 47*MB);             // 896 x 256B
  unsigned long long* amask = (unsigned long long*)(ws + 48*MB); // 32 KB
  float*          Mt    = (float*)(ws + 49*MB + 16*1024);   // 16 KB
  float*          selt  = (float*)(ws + 49*MB + 32*1024);   // 16 KB
  int*            flag  = (int*)  (ws + 49*MB + 48*1024);
  unsigned int*   rp    = (unsigned int*)(ws + 49*MB + 52*1024);  // 4 KB packed rules
  unsigned short* wpkh  = (unsigned short*)(ws + 49*MB + 64*1024);          // 256 KB
  unsigned short* wpkl  = (unsigned short*)(ws + 49*MB + 64*1024 + 256*1024); // 256 KB
  float*          ropet = (float*)(ws + 50*MB);             // 256 KB rope table

  detect_precompute_kernel<<<1, 256, 0, stream>>>(
      (const unsigned short*)x, flag, rq, rk, q_lg, k_lg, v_lg, o_lg, Mt, selt);
  mask_kernel<<<NTOK, 64, 0, stream>>>(rules, Mt, amask, rp);
  rope_tab_kernel<<<128, 256, 0, stream>>>(ropet);
  prep_wb_kernel<<<dim3(32, 4), 128, 0, stream>>>(q_si, k_si, v_si, o_si, wpkh, wpkl, flag);

  // QKV stage A (unified dtype handling — no dead launches)
  A_tt_mfma3<<<256, 256, 0, stream>>>(x, wpkh, wpkl, ttg, flag);
  A_hh3<<<NGRP, 256, 0, stream>>>(x, rules, q_ri, k_ri, v_ri, hhg, flag);

  // Stage B (rope via table)
  B_qkv<<<dim3(NGRP4, 3), 256, 0, stream>>>(ttg, hhg, rules, q_so, q_ro, k_so, k_ro, v_so, v_ro,
                                            selt, ropet, qb, kb, vb, flag);

  vtrans_kernel<<<dim3(16, 16, 4), 256, 0, stream>>>(vb, vtb);
  attn_mfma_kernel<<<dim3(23, BB, N_HEADS), 256, 0, stream>>>(qb, kb, vtb, rp, amask,
                                                              Obuf, mlbuf, qb);
  attn_combine<<<dim3(7, BB, N_HEADS), 256, 0, stream>>>(Obuf, mlbuf, qb);

  // o-projection (input fp32 from attn; weights dtype per flag)
  A_tt_mfma1<<<256, 256, 0, stream>>>(qb, wpkh, wpkl, ttg, flag);
  A_hh1<<<NGRP, 256, 0, stream>>>(qb, rules, o_ri, hhg, flag);
  B_o<<<NGRP4, 256, 0, stream>>>(ttg, hhg, rules, o_so, o_ro, selt + 3*1024, ropet, d_out, flag);
}